// Round 1
// baseline (674.788 us; speedup 1.0000x reference)
//
#include <hip/hip_runtime.h>
#include <math.h>

#define L_   4096
#define DM_  512
#define B_   4
#define H_   8
#define DK_  64
#define MTOT (B_*L_)      // 16384
#define TOPK 16

// ============================ SGEMM: C = A @ W^T + bias =====================
// A: M x K row-major.  W: N x K row-major (torch Linear weight).  256 threads,
// 128x64 tile, 8x4 micro-tile per thread.
// mode 0: C[m][n] flat (final output)
// mode 1: [b][h][l][d]  (V: d-contiguous for gather)
// mode 2: [b][h][d][l]  (Q,K: t-contiguous for FFT loads)
#define BM 128
#define BN 64
#define BK 16

__global__ __launch_bounds__(256)
void sgemm_kernel(const float* __restrict__ A, const float* __restrict__ W,
                  const float* __restrict__ bias, float* __restrict__ C,
                  int M, int N, int K, int mode)
{
  __shared__ __attribute__((aligned(16))) float As[BK][BM+4];
  __shared__ __attribute__((aligned(16))) float Bs[BK][BN+4];
  const int tid = threadIdx.x;
  const int m0 = blockIdx.x * BM;
  const int n0 = blockIdx.y * BN;
  const int tx = tid & 15, ty = tid >> 4;

  float acc[8][4];
#pragma unroll
  for (int i = 0; i < 8; i++)
#pragma unroll
    for (int j = 0; j < 4; j++) acc[i][j] = 0.f;

  for (int k0 = 0; k0 < K; k0 += BK) {
#pragma unroll
    for (int r = 0; r < 2; r++) {           // A tile: 128x16 = 512 float4
      int i = tid + 256*r;
      int m = i >> 2;
      int k4 = (i & 3) << 2;
      float4 v = *(const float4*)(A + (size_t)(m0+m)*K + (k0+k4));
      As[k4+0][m] = v.x; As[k4+1][m] = v.y; As[k4+2][m] = v.z; As[k4+3][m] = v.w;
    }
    {                                        // B tile: 64x16 = 256 float4
      int n = tid >> 2;
      int k4 = (tid & 3) << 2;
      float4 v = *(const float4*)(W + (size_t)(n0+n)*K + (k0+k4));
      Bs[k4+0][n] = v.x; Bs[k4+1][n] = v.y; Bs[k4+2][n] = v.z; Bs[k4+3][n] = v.w;
    }
    __syncthreads();
#pragma unroll
    for (int kk = 0; kk < BK; kk++) {
      float4 a0 = *(const float4*)&As[kk][ty*8];
      float4 a1 = *(const float4*)&As[kk][ty*8+4];
      float4 bv = *(const float4*)&Bs[kk][tx*4];
      float a[8] = {a0.x,a0.y,a0.z,a0.w,a1.x,a1.y,a1.z,a1.w};
      float b[4] = {bv.x,bv.y,bv.z,bv.w};
#pragma unroll
      for (int i = 0; i < 8; i++)
#pragma unroll
        for (int j = 0; j < 4; j++) acc[i][j] += a[i]*b[j];
    }
    __syncthreads();
  }

  float4 b4 = *(const float4*)(bias + n0 + tx*4);
  float bb[4] = {b4.x, b4.y, b4.z, b4.w};

  if (mode == 2) {
    // column-wise: 8 consecutive l per thread -> 2 float4 stores, t-contiguous
#pragma unroll
    for (int j = 0; j < 4; j++) {
      int n = n0 + tx*4 + j;
      int h = n >> 6, d = n & 63;
      int m = m0 + ty*8;
      int b = m >> 12, l = m & (L_-1);
      float* p = C + (((size_t)(b*H_ + h)*DK_ + d)*L_ + l);
      float4 v0 = make_float4(acc[0][j]+bb[j], acc[1][j]+bb[j], acc[2][j]+bb[j], acc[3][j]+bb[j]);
      float4 v1 = make_float4(acc[4][j]+bb[j], acc[5][j]+bb[j], acc[6][j]+bb[j], acc[7][j]+bb[j]);
      *(float4*)p = v0;
      *(float4*)(p+4) = v1;
    }
  } else if (mode == 1) {
#pragma unroll
    for (int i = 0; i < 8; i++) {
      int m = m0 + ty*8 + i;
      int b = m >> 12, l = m & (L_-1);
      int n = n0 + tx*4;
      int h = n >> 6, d = n & 63;
      float4 vv = make_float4(acc[i][0]+bb[0], acc[i][1]+bb[1], acc[i][2]+bb[2], acc[i][3]+bb[3]);
      *(float4*)(C + (((size_t)(b*H_ + h)*L_ + l)*DK_ + d)) = vv;
    }
  } else {
#pragma unroll
    for (int i = 0; i < 8; i++) {
      int m = m0 + ty*8 + i;
      float4 vv = make_float4(acc[i][0]+bb[0], acc[i][1]+bb[1], acc[i][2]+bb[2], acc[i][3]+bb[3]);
      *(float4*)(C + (size_t)m*N + n0 + tx*4) = vv;
    }
  }
}

// ============================ FFT (Stockham radix-2, N=4096) ================
// Forward DFT, e^{-i} convention, natural-order output. 12 stages, ping-pong
// A->B->A...; after 12 (even) stages the result is back in A.
// Verified identities: read indices are X[idx], X[idx+2048]; outputs
// Y[qi+2*pb], Y[qi+2*pb+s]; twiddle angle = -2*pi*pb/4096 with pb = idx&~(s-1).
__device__ __forceinline__ void fft12(float2* X, float2* Y, int tid)
{
#pragma unroll 1
  for (int sh = 0; sh < 12; sh++) {
    const int s = 1 << sh;
#pragma unroll
    for (int r = 0; r < 8; r++) {
      const int idx = tid + 256*r;
      const int qi = idx & (s-1);
      const int pb = idx - qi;                 // p << sh
      float2 a = X[idx];
      float2 b = X[idx + 2048];
      float ang = (-1.5339807878856412e-3f) * (float)pb;  // -2*pi/4096 * pb
      float wr, wi;
      __sincosf(ang, &wi, &wr);
      float tr = a.x - b.x, ti = a.y - b.y;
      int o = qi + (pb << 1);
      Y[o]     = make_float2(a.x + b.x, a.y + b.y);
      Y[o + s] = make_float2(tr*wr - ti*wi, tr*wi + ti*wr);
    }
    __syncthreads();
    float2* tmp = X; X = Y; Y = tmp;
  }
}

// One workgroup per (b*H+h, d-group of 4). Packs z = q + i*k, FFTs, unpacks
// Qf,Kf via Hermitian split, accumulates G = Qf*conj(Kf) over its 4 channels
// in registers, writes a partial spectrum (no atomics).
__global__ __launch_bounds__(256)
void fft_fwd_kernel(const float* __restrict__ Qt, const float* __restrict__ Kt,
                    float* __restrict__ P)
{
  __shared__ __attribute__((aligned(16))) float2 Abuf[L_];
  __shared__ __attribute__((aligned(16))) float2 Bbuf[L_];
  const int tid = threadIdx.x;
  const int bh = blockIdx.x;      // 0..31
  const int g  = blockIdx.y;      // 0..15
  float2 accv[16];
#pragma unroll
  for (int r = 0; r < 16; r++) accv[r] = make_float2(0.f, 0.f);

  for (int dd = 0; dd < 4; dd++) {
    int d = g*4 + dd;
    const float* q = Qt + ((size_t)bh*DK_ + d)*L_;
    const float* k = Kt + ((size_t)bh*DK_ + d)*L_;
    __syncthreads();              // previous iteration's unpack reads done
#pragma unroll
    for (int r = 0; r < 4; r++) {
      int t = (tid + 256*r)*4;
      float4 qv = *(const float4*)(q + t);
      float4 kv = *(const float4*)(k + t);
      *(float4*)&Abuf[t]   = make_float4(qv.x, kv.x, qv.y, kv.y);
      *(float4*)&Abuf[t+2] = make_float4(qv.z, kv.z, qv.w, kv.w);
    }
    __syncthreads();
    fft12(Abuf, Bbuf, tid);       // ends with a barrier, result in Abuf
#pragma unroll
    for (int r = 0; r < 16; r++) {
      int f = tid + 256*r;
      float2 zf = Abuf[f];
      float2 zc = Abuf[(L_ - f) & (L_-1)];
      float qr = 0.5f*(zf.x + zc.x);       // Qf = (Z[f]+conj(Z[N-f]))/2
      float qi = 0.5f*(zf.y - zc.y);
      float kr = 0.5f*(zf.y + zc.y);       // Kf = (Z[f]-conj(Z[N-f]))/(2i)
      float ki = 0.5f*(zc.x - zf.x);
      accv[r].x += qr*kr + qi*ki;          // G = Qf * conj(Kf)
      accv[r].y += qi*kr - qr*ki;
    }
  }
  float2* Pp = (float2*)P + ((size_t)bh*16 + g)*L_;
#pragma unroll
  for (int r = 0; r < 16; r++) Pp[tid + 256*r] = accv[r];
}

// One workgroup per (b,h): sum 16 partial spectra, inverse via
// corr = Re(FFT(conj(S)))/N, scaled by 1/Dk for the mean over d.
__global__ __launch_bounds__(256)
void fft_inv_kernel(const float* __restrict__ P, float* __restrict__ corr)
{
  __shared__ __attribute__((aligned(16))) float2 Abuf[L_];
  __shared__ __attribute__((aligned(16))) float2 Bbuf[L_];
  const int tid = threadIdx.x;
  const int bh = blockIdx.x;
  const float2* Pp = (const float2*)P + (size_t)bh*16*L_;
#pragma unroll 1
  for (int r = 0; r < 16; r++) {
    int f = tid + 256*r;
    float sr = 0.f, si = 0.f;
#pragma unroll
    for (int g = 0; g < 16; g++) { float2 v = Pp[(size_t)g*L_ + f]; sr += v.x; si += v.y; }
    Abuf[f] = make_float2(sr, -si);
  }
  __syncthreads();
  fft12(Abuf, Bbuf, tid);
  const float scale = 1.0f / ((float)L_ * (float)DK_);
#pragma unroll
  for (int r = 0; r < 16; r++) {
    int f = tid + 256*r;
    corr[(size_t)bh*L_ + f] = Abuf[f].x * scale;
  }
}

// ============================ top-16 + softmax ==============================
__global__ __launch_bounds__(256)
void topk_kernel(const float* __restrict__ corr, float* __restrict__ w,
                 int* __restrict__ delays)
{
  __shared__ float vals[L_];
  __shared__ float sv[256];
  __shared__ int   si[256];
  __shared__ float topv_s[TOPK];
  __shared__ int   topi_s[TOPK];
  const int tid = threadIdx.x;
  const int bh = blockIdx.x;
#pragma unroll
  for (int r = 0; r < 16; r++) vals[tid + 256*r] = corr[(size_t)bh*L_ + tid + 256*r];
  __syncthreads();
  for (int it = 0; it < TOPK; it++) {
    float bv = -INFINITY; int bi = 0;
#pragma unroll
    for (int r = 0; r < 16; r++) {
      int i = tid + 256*r;
      float v = vals[i];
      if (v > bv) { bv = v; bi = i; }       // lowest index wins ties
    }
    sv[tid] = bv; si[tid] = bi;
    __syncthreads();
    for (int off = 128; off > 0; off >>= 1) {
      if (tid < off) {
        float v2 = sv[tid+off]; int i2 = si[tid+off];
        if (v2 > sv[tid] || (v2 == sv[tid] && i2 < si[tid])) { sv[tid] = v2; si[tid] = i2; }
      }
      __syncthreads();
    }
    if (tid == 0) { topv_s[it] = sv[0]; topi_s[it] = si[0]; vals[si[0]] = -INFINITY; }
    __syncthreads();
  }
  if (tid == 0) {
    float mx = topv_s[0];
    for (int j = 1; j < TOPK; j++) mx = fmaxf(mx, topv_s[j]);
    float e[TOPK]; float se = 0.f;
    for (int j = 0; j < TOPK; j++) { e[j] = expf(topv_s[j] - mx); se += e[j]; }
    float inv = 1.0f / se;
    for (int j = 0; j < TOPK; j++) {
      w[bh*TOPK + j] = e[j] * inv;
      delays[bh*TOPK + j] = topi_s[j];
    }
  }
}

// ============================ delay gather ==================================
// ctx[b][t][h*64+d] = sum_j w_j * V[b][h][(t - delay_j) mod L][d]
__global__ __launch_bounds__(256)
void gather_kernel(const float* __restrict__ V, const float* __restrict__ w,
                   const int* __restrict__ delays, float* __restrict__ ctx)
{
  const int bh = blockIdx.x;
  const int b = bh >> 3, h = bh & 7;
  const int t0 = blockIdx.y * 16;
  __shared__ float ws[TOPK];
  __shared__ int   dls[TOPK];
  const int tid = threadIdx.x;
  if (tid < TOPK) { ws[tid] = w[bh*TOPK + tid]; dls[tid] = delays[bh*TOPK + tid]; }
  __syncthreads();
  const int t  = t0 + (tid >> 4);
  const int d4 = (tid & 15) * 4;
  const float* Vh = V + (size_t)bh * L_ * DK_;
  float4 acc = make_float4(0.f, 0.f, 0.f, 0.f);
#pragma unroll
  for (int j = 0; j < TOPK; j++) {
    int row = (t - dls[j]) & (L_-1);
    float4 v = *(const float4*)(Vh + (size_t)row*DK_ + d4);
    float wj = ws[j];
    acc.x += wj*v.x; acc.y += wj*v.y; acc.z += wj*v.z; acc.w += wj*v.w;
  }
  *(float4*)(ctx + ((size_t)(b*L_ + t)*DM_) + h*DK_ + d4) = acc;
}

// ============================ launch ========================================
extern "C" void kernel_launch(void* const* d_in, const int* in_sizes, int n_in,
                              void* d_out, int out_size, void* d_ws, size_t ws_size,
                              hipStream_t stream)
{
  const float* x  = (const float*)d_in[0];
  const float* Wq = (const float*)d_in[1];
  const float* bq = (const float*)d_in[2];
  const float* Wk = (const float*)d_in[3];
  const float* bk = (const float*)d_in[4];
  const float* Wv = (const float*)d_in[5];
  const float* bv = (const float*)d_in[6];
  const float* Wo = (const float*)d_in[7];
  const float* bo = (const float*)d_in[8];
  float* out = (float*)d_out;
  float* ws  = (float*)d_ws;

  // workspace layout (floats); ctx aliases Qt (Qt dead after fft_fwd)
  float* Qt   = ws;                       //  8,388,608  [b][h][d][t]
  float* Kt   = ws +  8388608;            //  8,388,608  [b][h][d][t]
  float* Vv   = ws + 16777216;            //  8,388,608  [b][h][t][d]
  float* P    = ws + 25165824;            //  4,194,304  partial spectra (float2)
  float* corr = ws + 29360128;            //    131,072
  float* wbuf = ws + 29491200;            //        512
  int*   dbuf = (int*)(ws + 29491712);    //        512
  float* ctx  = Qt;                       //  [b][t][h*64+d]

  dim3 gGemm(MTOT/BM, DM_/BN);            // (128, 8)
  sgemm_kernel<<<gGemm, 256, 0, stream>>>(x, Wq, bq, Qt, MTOT, DM_, DM_, 2);
  sgemm_kernel<<<gGemm, 256, 0, stream>>>(x, Wk, bk, Kt, MTOT, DM_, DM_, 2);
  sgemm_kernel<<<gGemm, 256, 0, stream>>>(x, Wv, bv, Vv, MTOT, DM_, DM_, 1);

  fft_fwd_kernel<<<dim3(32, 16), 256, 0, stream>>>(Qt, Kt, P);
  fft_inv_kernel<<<32, 256, 0, stream>>>(P, corr);
  topk_kernel<<<32, 256, 0, stream>>>(corr, wbuf, dbuf);
  gather_kernel<<<dim3(32, L_/16), 256, 0, stream>>>(Vv, wbuf, dbuf, ctx);

  sgemm_kernel<<<gGemm, 256, 0, stream>>>(ctx, Wo, bo, out, MTOT, DM_, DM_, 0);
}

// Round 2
// 334.119 us; speedup vs baseline: 2.0196x; 2.0196x over previous
//
#include <hip/hip_runtime.h>
#include <math.h>

#define L_   4096
#define DM_  512
#define B_   4
#define H_   8
#define DK_  64
#define MTOT (B_*L_)      // 16384
#define TOPK 16

typedef __bf16 bf16x8 __attribute__((ext_vector_type(8)));
typedef float  f32x4  __attribute__((ext_vector_type(4)));

// ---------------------------------------------------------------- helpers ---
__device__ __forceinline__ void splitf(float x, unsigned short& h, unsigned short& l) {
  unsigned int u = __float_as_uint(x);
  h = (unsigned short)(u >> 16);                       // truncated hi
  float hf = __uint_as_float(u & 0xFFFF0000u);
  l = (unsigned short)(__float_as_uint(x - hf) >> 16); // truncated lo
}
__device__ __forceinline__ unsigned short f2bf_rne(float f) {
  unsigned int u = __float_as_uint(f);
  return (unsigned short)((u + 0x7FFFu + ((u >> 16) & 1u)) >> 16);
}
__device__ __forceinline__ float bf2f(unsigned short u) {
  return __uint_as_float(((unsigned int)u) << 16);
}

// async 16B/lane global->LDS stage of a 128x32 bf16 tile from a row-major
// source with row stride 512 elements. LDS layout: [128][32] contiguous.
__device__ __forceinline__ void stage_tile_async(const unsigned short* __restrict__ g,
                                                 int row0, int k0,
                                                 unsigned short* lds, int tid) {
  const int wave = tid >> 6;
#pragma unroll
  for (int it = 0; it < 2; ++it) {
    int slot = it * 256 + tid;          // 0..511
    int row  = slot >> 2;               // 0..127
    int ch   = slot & 3;                // 16B chunk within 64B row
    const unsigned short* gp = g + (size_t)(row0 + row) * 512 + k0 + ch * 8;
    unsigned short* lp = lds + (size_t)(it * 256 + wave * 64) * 8;  // wave-uniform base
    __builtin_amdgcn_global_load_lds(
        (const __attribute__((address_space(1))) unsigned int*)gp,
        (__attribute__((address_space(3))) unsigned int*)lp, 16, 0, 0);
  }
}

// ====================== MFMA GEMM: C = A @ W^T + bias =======================
// M=16384, N=512, K=512. 128x128 block tile, BK=32, 256 thr (4 waves 2x2).
// 3-pass split bf16: AhBh + AhBl + AlBh  (~fp32 accuracy).
// ASPLIT=true:  A from pre-split bf16 arrays (async staging)
// ASPLIT=false: A fp32, split in-kernel during staging
// MODE 0: C fp32 [m][n]        MODE 1: C bf16 [b][h][l][d]   MODE 2: C fp32 [b][h][d][l]
template<int MODE, bool ASPLIT>
__global__ __launch_bounds__(256)
void mfma_gemm(const float* __restrict__ Afp,
               const unsigned short* __restrict__ Ah, const unsigned short* __restrict__ Al,
               const unsigned short* __restrict__ Bh, const unsigned short* __restrict__ Bl,
               const float* __restrict__ bias, void* __restrict__ Cout)
{
  __shared__ __attribute__((aligned(16))) unsigned short AhS[128 * 32];
  __shared__ __attribute__((aligned(16))) unsigned short AlS[128 * 32];
  __shared__ __attribute__((aligned(16))) unsigned short BhS[128 * 32];
  __shared__ __attribute__((aligned(16))) unsigned short BlS[128 * 32];

  const int tid  = threadIdx.x;
  const int lane = tid & 63, wave = tid >> 6;
  const int m0 = blockIdx.x * 128, n0 = blockIdx.y * 128;
  const int wm = (wave >> 1) * 64, wn = (wave & 1) * 64;
  const int fr = lane & 15, fq = lane >> 4;

  f32x4 acc[4][4];
#pragma unroll
  for (int i = 0; i < 4; i++)
#pragma unroll
    for (int j = 0; j < 4; j++) acc[i][j] = (f32x4){0.f, 0.f, 0.f, 0.f};

  for (int k0 = 0; k0 < 512; k0 += 32) {
    if (ASPLIT) {
      stage_tile_async(Ah, m0, k0, AhS, tid);
      stage_tile_async(Al, m0, k0, AlS, tid);
    }
    stage_tile_async(Bh, n0, k0, BhS, tid);
    stage_tile_async(Bl, n0, k0, BlS, tid);
    if (!ASPLIT) {
#pragma unroll
      for (int it = 0; it < 4; ++it) {
        int c = it * 256 + tid;            // 0..1023 float4-chunks
        int row = c >> 3, col = (c & 7) * 4;
        float4 v = *(const float4*)(Afp + (size_t)(m0 + row) * 512 + k0 + col);
        ushort4 h, l;
        splitf(v.x, h.x, l.x); splitf(v.y, h.y, l.y);
        splitf(v.z, h.z, l.z); splitf(v.w, h.w, l.w);
        *(ushort4*)&AhS[row * 32 + col] = h;
        *(ushort4*)&AlS[row * 32 + col] = l;
      }
    }
    __syncthreads();

    bf16x8 ah[4], al[4], bh[4], bl[4];
#pragma unroll
    for (int t = 0; t < 4; ++t) {
      ah[t] = *(const bf16x8*)&AhS[(wm + t * 16 + fr) * 32 + fq * 8];
      al[t] = *(const bf16x8*)&AlS[(wm + t * 16 + fr) * 32 + fq * 8];
      bh[t] = *(const bf16x8*)&BhS[(wn + t * 16 + fr) * 32 + fq * 8];
      bl[t] = *(const bf16x8*)&BlS[(wn + t * 16 + fr) * 32 + fq * 8];
    }
#pragma unroll
    for (int mt = 0; mt < 4; ++mt)
#pragma unroll
      for (int nt = 0; nt < 4; ++nt) {
        acc[mt][nt] = __builtin_amdgcn_mfma_f32_16x16x32_bf16(ah[mt], bh[nt], acc[mt][nt], 0, 0, 0);
        acc[mt][nt] = __builtin_amdgcn_mfma_f32_16x16x32_bf16(ah[mt], bl[nt], acc[mt][nt], 0, 0, 0);
        acc[mt][nt] = __builtin_amdgcn_mfma_f32_16x16x32_bf16(al[mt], bh[nt], acc[mt][nt], 0, 0, 0);
      }
    __syncthreads();
  }

  // epilogue: D[row=fq*4+r][col=fr] per 16x16 tile
#pragma unroll
  for (int nt = 0; nt < 4; ++nt) {
    const int n = n0 + wn + nt * 16 + fr;
    const float bb = bias[n];
#pragma unroll
    for (int mt = 0; mt < 4; ++mt) {
      const int mb = m0 + wm + mt * 16 + fq * 4;
      f32x4 a = acc[mt][nt];
      if (MODE == 2) {
        const int h = n >> 6, d = n & 63;
        const int b = mb >> 12, l0 = mb & (L_ - 1);
        float4 st = make_float4(a[0] + bb, a[1] + bb, a[2] + bb, a[3] + bb);
        *(float4*)((float*)Cout + ((size_t)(b * H_ + h) * DK_ + d) * L_ + l0) = st;
      } else if (MODE == 1) {
        const int h = n >> 6, d = n & 63;
#pragma unroll
        for (int r = 0; r < 4; ++r) {
          int m = mb + r;
          int b = m >> 12, l = m & (L_ - 1);
          ((unsigned short*)Cout)[((size_t)(b * H_ + h) * L_ + l) * DK_ + d] = f2bf_rne(a[r] + bb);
        }
      } else {
#pragma unroll
        for (int r = 0; r < 4; ++r) {
          int m = mb + r;
          ((float*)Cout)[(size_t)m * DM_ + n] = a[r] + bb;
        }
      }
    }
  }
}

// ====================== fp32 -> (hi,lo) bf16 split (weights) ================
__global__ __launch_bounds__(256)
void split_kernel(const float* __restrict__ in, unsigned short* __restrict__ hi,
                  unsigned short* __restrict__ lo, int n4)
{
  int i = blockIdx.x * 256 + threadIdx.x;
  if (i >= n4) return;
  float4 v = ((const float4*)in)[i];
  ushort4 h, l;
  splitf(v.x, h.x, l.x); splitf(v.y, h.y, l.y);
  splitf(v.z, h.z, l.z); splitf(v.w, h.w, l.w);
  ((ushort4*)hi)[i] = h;
  ((ushort4*)lo)[i] = l;
}

// ============================ FFT (Stockham radix-2, N=4096) ================
__device__ __forceinline__ void fft12(float2* X, float2* Y, int tid)
{
#pragma unroll 1
  for (int sh = 0; sh < 12; sh++) {
    const int s = 1 << sh;
#pragma unroll
    for (int r = 0; r < 8; r++) {
      const int idx = tid + 256 * r;
      const int qi = idx & (s - 1);
      const int pb = idx - qi;
      float2 a = X[idx];
      float2 b = X[idx + 2048];
      float ang = (-1.5339807878856412e-3f) * (float)pb;  // -2*pi/4096 * pb
      float wr, wi;
      __sincosf(ang, &wi, &wr);
      float tr = a.x - b.x, ti = a.y - b.y;
      int o = qi + (pb << 1);
      Y[o]     = make_float2(a.x + b.x, a.y + b.y);
      Y[o + s] = make_float2(tr * wr - ti * wi, tr * wi + ti * wr);
    }
    __syncthreads();
    float2* tmp = X; X = Y; Y = tmp;
  }
}

__global__ __launch_bounds__(256)
void fft_fwd_kernel(const float* __restrict__ Qt, const float* __restrict__ Kt,
                    float* __restrict__ P)
{
  __shared__ __attribute__((aligned(16))) float2 Abuf[L_];
  __shared__ __attribute__((aligned(16))) float2 Bbuf[L_];
  const int tid = threadIdx.x;
  const int bh = blockIdx.x;
  const int g  = blockIdx.y;
  float2 accv[16];
#pragma unroll
  for (int r = 0; r < 16; r++) accv[r] = make_float2(0.f, 0.f);

  for (int dd = 0; dd < 4; dd++) {
    int d = g * 4 + dd;
    const float* q = Qt + ((size_t)bh * DK_ + d) * L_;
    const float* k = Kt + ((size_t)bh * DK_ + d) * L_;
    __syncthreads();
#pragma unroll
    for (int r = 0; r < 4; r++) {
      int t = (tid + 256 * r) * 4;
      float4 qv = *(const float4*)(q + t);
      float4 kv = *(const float4*)(k + t);
      *(float4*)&Abuf[t]     = make_float4(qv.x, kv.x, qv.y, kv.y);
      *(float4*)&Abuf[t + 2] = make_float4(qv.z, kv.z, qv.w, kv.w);
    }
    __syncthreads();
    fft12(Abuf, Bbuf, tid);
#pragma unroll
    for (int r = 0; r < 16; r++) {
      int f = tid + 256 * r;
      float2 zf = Abuf[f];
      float2 zc = Abuf[(L_ - f) & (L_ - 1)];
      float qr = 0.5f * (zf.x + zc.x);
      float qi = 0.5f * (zf.y - zc.y);
      float kr = 0.5f * (zf.y + zc.y);
      float ki = 0.5f * (zc.x - zf.x);
      accv[r].x += qr * kr + qi * ki;
      accv[r].y += qi * kr - qr * ki;
    }
  }
  float2* Pp = (float2*)P + ((size_t)bh * 16 + g) * L_;
#pragma unroll
  for (int r = 0; r < 16; r++) Pp[tid + 256 * r] = accv[r];
}

__global__ __launch_bounds__(256)
void fft_inv_kernel(const float* __restrict__ P, float* __restrict__ corr)
{
  __shared__ __attribute__((aligned(16))) float2 Abuf[L_];
  __shared__ __attribute__((aligned(16))) float2 Bbuf[L_];
  const int tid = threadIdx.x;
  const int bh = blockIdx.x;
  const float2* Pp = (const float2*)P + (size_t)bh * 16 * L_;
#pragma unroll 1
  for (int r = 0; r < 16; r++) {
    int f = tid + 256 * r;
    float sr = 0.f, si = 0.f;
#pragma unroll
    for (int g = 0; g < 16; g++) { float2 v = Pp[(size_t)g * L_ + f]; sr += v.x; si += v.y; }
    Abuf[f] = make_float2(sr, -si);
  }
  __syncthreads();
  fft12(Abuf, Bbuf, tid);
  const float scale = 1.0f / ((float)L_ * (float)DK_);
#pragma unroll
  for (int r = 0; r < 16; r++) {
    int f = tid + 256 * r;
    corr[(size_t)bh * L_ + f] = Abuf[f].x * scale;
  }
}

// ============================ top-16 + softmax ==============================
__global__ __launch_bounds__(256)
void topk_kernel(const float* __restrict__ corr, float* __restrict__ w,
                 int* __restrict__ delays)
{
  __shared__ float vals[L_];
  __shared__ float sv[256];
  __shared__ int   si[256];
  __shared__ float topv_s[TOPK];
  __shared__ int   topi_s[TOPK];
  const int tid = threadIdx.x;
  const int bh = blockIdx.x;
#pragma unroll
  for (int r = 0; r < 16; r++) vals[tid + 256 * r] = corr[(size_t)bh * L_ + tid + 256 * r];
  __syncthreads();
  for (int it = 0; it < TOPK; it++) {
    float bv = -INFINITY; int bi = 0;
#pragma unroll
    for (int r = 0; r < 16; r++) {
      int i = tid + 256 * r;
      float v = vals[i];
      if (v > bv) { bv = v; bi = i; }
    }
    sv[tid] = bv; si[tid] = bi;
    __syncthreads();
    for (int off = 128; off > 0; off >>= 1) {
      if (tid < off) {
        float v2 = sv[tid + off]; int i2 = si[tid + off];
        if (v2 > sv[tid] || (v2 == sv[tid] && i2 < si[tid])) { sv[tid] = v2; si[tid] = i2; }
      }
      __syncthreads();
    }
    if (tid == 0) { topv_s[it] = sv[0]; topi_s[it] = si[0]; vals[si[0]] = -INFINITY; }
    __syncthreads();
  }
  if (tid == 0) {
    float mx = topv_s[0];
    for (int j = 1; j < TOPK; j++) mx = fmaxf(mx, topv_s[j]);
    float e[TOPK]; float se = 0.f;
    for (int j = 0; j < TOPK; j++) { e[j] = expf(topv_s[j] - mx); se += e[j]; }
    float inv = 1.0f / se;
    for (int j = 0; j < TOPK; j++) {
      w[bh * TOPK + j] = e[j] * inv;
      delays[bh * TOPK + j] = topi_s[j];
    }
  }
}

// ============================ delay gather ==================================
// V bf16 [b][h][t][d]; writes ctx pre-split (hi/lo bf16) for the O-GEMM.
__global__ __launch_bounds__(256)
void gather_kernel(const unsigned short* __restrict__ V, const float* __restrict__ w,
                   const int* __restrict__ delays,
                   unsigned short* __restrict__ ctxh, unsigned short* __restrict__ ctxl)
{
  const int bh = blockIdx.x;
  const int b = bh >> 3, h = bh & 7;
  const int t0 = blockIdx.y * 16;
  __shared__ float ws[TOPK];
  __shared__ int   dls[TOPK];
  const int tid = threadIdx.x;
  if (tid < TOPK) { ws[tid] = w[bh * TOPK + tid]; dls[tid] = delays[bh * TOPK + tid]; }
  __syncthreads();
  const int t  = t0 + (tid >> 4);
  const int d4 = (tid & 15) * 4;
  const unsigned short* Vh = V + (size_t)bh * L_ * DK_;
  float ax = 0.f, ay = 0.f, az = 0.f, aw = 0.f;
#pragma unroll
  for (int j = 0; j < TOPK; j++) {
    int row = (t - dls[j]) & (L_ - 1);
    ushort4 v = *(const ushort4*)(Vh + (size_t)row * DK_ + d4);
    float wj = ws[j];
    ax += wj * bf2f(v.x); ay += wj * bf2f(v.y);
    az += wj * bf2f(v.z); aw += wj * bf2f(v.w);
  }
  ushort4 h4, l4;
  splitf(ax, h4.x, l4.x); splitf(ay, h4.y, l4.y);
  splitf(az, h4.z, l4.z); splitf(aw, h4.w, l4.w);
  size_t off = ((size_t)(b * L_ + t) * DM_) + h * DK_ + d4;
  *(ushort4*)(ctxh + off) = h4;
  *(ushort4*)(ctxl + off) = l4;
}

// ============================ launch ========================================
extern "C" void kernel_launch(void* const* d_in, const int* in_sizes, int n_in,
                              void* d_out, int out_size, void* d_ws, size_t ws_size,
                              hipStream_t stream)
{
  const float* x  = (const float*)d_in[0];
  const float* Wq = (const float*)d_in[1];
  const float* bq = (const float*)d_in[2];
  const float* Wk = (const float*)d_in[3];
  const float* bk = (const float*)d_in[4];
  const float* Wv = (const float*)d_in[5];
  const float* bv = (const float*)d_in[6];
  const float* Wo = (const float*)d_in[7];
  const float* bo = (const float*)d_in[8];
  float* out = (float*)d_out;
  float* ws  = (float*)d_ws;

  // workspace layout (float indices). Peak ~105.4 MB.
  float* Qt = ws;                                   // 8,388,608 f  [b][h][d][t]
  float* Kt = ws + 8388608;                         // 8,388,608 f  [b][h][d][t]
  unsigned short* Vv = (unsigned short*)(ws + 16777216);   // 8,388,608 bf16 [b][h][t][d]
  float* P  = ws + 20971520;                        // 4,194,304 f  partial spectra
  unsigned short* Wsp = (unsigned short*)(ws + 25165824);  // 8 x 262,144 bf16
  float* corr = ws + 26214400;                      // 131,072 f
  float* wbuf = ws + 26345472;                      // 512
  int*   dbuf = (int*)(ws + 26345984);              // 512
  // ctx splits alias Qt (dead after fft_fwd)
  unsigned short* ctxh = (unsigned short*)ws;               // 8,388,608 bf16
  unsigned short* ctxl = (unsigned short*)(ws + 4194304);   // 8,388,608 bf16

  unsigned short* Wqh = Wsp;            unsigned short* Wql = Wsp + 262144;
  unsigned short* Wkh = Wsp + 524288;   unsigned short* Wkl = Wsp + 786432;
  unsigned short* Wvh = Wsp + 1048576;  unsigned short* Wvl = Wsp + 1310720;
  unsigned short* Woh = Wsp + 1572864;  unsigned short* Wol = Wsp + 1835008;

  split_kernel<<<256, 256, 0, stream>>>(Wq, Wqh, Wql, 65536);
  split_kernel<<<256, 256, 0, stream>>>(Wk, Wkh, Wkl, 65536);
  split_kernel<<<256, 256, 0, stream>>>(Wv, Wvh, Wvl, 65536);
  split_kernel<<<256, 256, 0, stream>>>(Wo, Woh, Wol, 65536);

  dim3 gGemm(MTOT / 128, DM_ / 128);    // (128, 4)
  mfma_gemm<2, false><<<gGemm, 256, 0, stream>>>(x, nullptr, nullptr, Wqh, Wql, bq, Qt);
  mfma_gemm<2, false><<<gGemm, 256, 0, stream>>>(x, nullptr, nullptr, Wkh, Wkl, bk, Kt);
  mfma_gemm<1, false><<<gGemm, 256, 0, stream>>>(x, nullptr, nullptr, Wvh, Wvl, bv, Vv);

  fft_fwd_kernel<<<dim3(32, 16), 256, 0, stream>>>(Qt, Kt, P);
  fft_inv_kernel<<<32, 256, 0, stream>>>(P, corr);
  topk_kernel<<<32, 256, 0, stream>>>(corr, wbuf, dbuf);
  gather_kernel<<<dim3(32, L_ / 16), 256, 0, stream>>>(Vv, wbuf, dbuf, ctxh, ctxl);

  mfma_gemm<0, true><<<gGemm, 256, 0, stream>>>(nullptr, ctxh, ctxl, Woh, Wol, bo, out);
}

// Round 3
// 315.920 us; speedup vs baseline: 2.1359x; 1.0576x over previous
//
#include <hip/hip_runtime.h>
#include <math.h>

#define L_   4096
#define DM_  512
#define B_   4
#define H_   8
#define DK_  64
#define MTOT (B_*L_)      // 16384
#define TOPK 16

typedef __bf16 bf16x8 __attribute__((ext_vector_type(8)));
typedef float  f32x4  __attribute__((ext_vector_type(4)));

// ---------------------------------------------------------------- helpers ---
__device__ __forceinline__ void splitf(float x, unsigned short& h, unsigned short& l) {
  unsigned int u = __float_as_uint(x);
  h = (unsigned short)(u >> 16);                       // truncated hi
  float hf = __uint_as_float(u & 0xFFFF0000u);
  l = (unsigned short)(__float_as_uint(x - hf) >> 16); // truncated lo
}
__device__ __forceinline__ unsigned short f2bf_rne(float f) {
  unsigned int u = __float_as_uint(f);
  return (unsigned short)((u + 0x7FFFu + ((u >> 16) & 1u)) >> 16);
}
__device__ __forceinline__ float bf2f(unsigned short u) {
  return __uint_as_float(((unsigned int)u) << 16);
}

// async 16B/lane global->LDS stage of a 128x32 bf16 tile from a row-major
// source with row stride 512 elements. LDS layout: [128][32] contiguous.
__device__ __forceinline__ void stage_tile_async(const unsigned short* __restrict__ g,
                                                 int row0, int k0,
                                                 unsigned short* lds, int tid) {
  const int wave = tid >> 6;
#pragma unroll
  for (int it = 0; it < 2; ++it) {
    int slot = it * 256 + tid;          // 0..511
    int row  = slot >> 2;               // 0..127
    int ch   = slot & 3;                // 16B chunk within 64B row
    const unsigned short* gp = g + (size_t)(row0 + row) * 512 + k0 + ch * 8;
    unsigned short* lp = lds + (size_t)(it * 256 + wave * 64) * 8;  // wave-uniform base
    __builtin_amdgcn_global_load_lds(
        (const __attribute__((address_space(1))) unsigned int*)gp,
        (__attribute__((address_space(3))) unsigned int*)lp, 16, 0, 0);
  }
}

// ====================== MFMA GEMM: C = A @ W^T + bias =======================
template<int MODE, bool ASPLIT>
__global__ __launch_bounds__(256)
void mfma_gemm(const float* __restrict__ Afp,
               const unsigned short* __restrict__ Ah, const unsigned short* __restrict__ Al,
               const unsigned short* __restrict__ Bh, const unsigned short* __restrict__ Bl,
               const float* __restrict__ bias, void* __restrict__ Cout)
{
  __shared__ __attribute__((aligned(16))) unsigned short AhS[128 * 32];
  __shared__ __attribute__((aligned(16))) unsigned short AlS[128 * 32];
  __shared__ __attribute__((aligned(16))) unsigned short BhS[128 * 32];
  __shared__ __attribute__((aligned(16))) unsigned short BlS[128 * 32];

  const int tid  = threadIdx.x;
  const int lane = tid & 63, wave = tid >> 6;
  const int m0 = blockIdx.x * 128, n0 = blockIdx.y * 128;
  const int wm = (wave >> 1) * 64, wn = (wave & 1) * 64;
  const int fr = lane & 15, fq = lane >> 4;

  f32x4 acc[4][4];
#pragma unroll
  for (int i = 0; i < 4; i++)
#pragma unroll
    for (int j = 0; j < 4; j++) acc[i][j] = (f32x4){0.f, 0.f, 0.f, 0.f};

  for (int k0 = 0; k0 < 512; k0 += 32) {
    if (ASPLIT) {
      stage_tile_async(Ah, m0, k0, AhS, tid);
      stage_tile_async(Al, m0, k0, AlS, tid);
    }
    stage_tile_async(Bh, n0, k0, BhS, tid);
    stage_tile_async(Bl, n0, k0, BlS, tid);
    if (!ASPLIT) {
#pragma unroll
      for (int it = 0; it < 4; ++it) {
        int c = it * 256 + tid;            // 0..1023 float4-chunks
        int row = c >> 3, col = (c & 7) * 4;
        float4 v = *(const float4*)(Afp + (size_t)(m0 + row) * 512 + k0 + col);
        ushort4 h, l;
        splitf(v.x, h.x, l.x); splitf(v.y, h.y, l.y);
        splitf(v.z, h.z, l.z); splitf(v.w, h.w, l.w);
        *(ushort4*)&AhS[row * 32 + col] = h;
        *(ushort4*)&AlS[row * 32 + col] = l;
      }
    }
    __syncthreads();

    bf16x8 ah[4], al[4], bh[4], bl[4];
#pragma unroll
    for (int t = 0; t < 4; ++t) {
      ah[t] = *(const bf16x8*)&AhS[(wm + t * 16 + fr) * 32 + fq * 8];
      al[t] = *(const bf16x8*)&AlS[(wm + t * 16 + fr) * 32 + fq * 8];
      bh[t] = *(const bf16x8*)&BhS[(wn + t * 16 + fr) * 32 + fq * 8];
      bl[t] = *(const bf16x8*)&BlS[(wn + t * 16 + fr) * 32 + fq * 8];
    }
#pragma unroll
    for (int mt = 0; mt < 4; ++mt)
#pragma unroll
      for (int nt = 0; nt < 4; ++nt) {
        acc[mt][nt] = __builtin_amdgcn_mfma_f32_16x16x32_bf16(ah[mt], bh[nt], acc[mt][nt], 0, 0, 0);
        acc[mt][nt] = __builtin_amdgcn_mfma_f32_16x16x32_bf16(ah[mt], bl[nt], acc[mt][nt], 0, 0, 0);
        acc[mt][nt] = __builtin_amdgcn_mfma_f32_16x16x32_bf16(al[mt], bh[nt], acc[mt][nt], 0, 0, 0);
      }
    __syncthreads();
  }

#pragma unroll
  for (int nt = 0; nt < 4; ++nt) {
    const int n = n0 + wn + nt * 16 + fr;
    const float bb = bias[n];
#pragma unroll
    for (int mt = 0; mt < 4; ++mt) {
      const int mb = m0 + wm + mt * 16 + fq * 4;
      f32x4 a = acc[mt][nt];
      if (MODE == 2) {
        const int h = n >> 6, d = n & 63;
        const int b = mb >> 12, l0 = mb & (L_ - 1);
        float4 st = make_float4(a[0] + bb, a[1] + bb, a[2] + bb, a[3] + bb);
        *(float4*)((float*)Cout + ((size_t)(b * H_ + h) * DK_ + d) * L_ + l0) = st;
      } else if (MODE == 1) {
        const int h = n >> 6, d = n & 63;
#pragma unroll
        for (int r = 0; r < 4; ++r) {
          int m = mb + r;
          int b = m >> 12, l = m & (L_ - 1);
          ((unsigned short*)Cout)[((size_t)(b * H_ + h) * L_ + l) * DK_ + d] = f2bf_rne(a[r] + bb);
        }
      } else {
#pragma unroll
        for (int r = 0; r < 4; ++r) {
          int m = mb + r;
          ((float*)Cout)[(size_t)m * DM_ + n] = a[r] + bb;
        }
      }
    }
  }
}

// ====================== fp32 -> (hi,lo) bf16 split (weights) ================
__global__ __launch_bounds__(256)
void split_kernel(const float* __restrict__ in, unsigned short* __restrict__ hi,
                  unsigned short* __restrict__ lo, int n4)
{
  int i = blockIdx.x * 256 + threadIdx.x;
  if (i >= n4) return;
  float4 v = ((const float4*)in)[i];
  ushort4 h, l;
  splitf(v.x, h.x, l.x); splitf(v.y, h.y, l.y);
  splitf(v.z, h.z, l.z); splitf(v.w, h.w, l.w);
  ((ushort4*)hi)[i] = h;
  ((ushort4*)lo)[i] = l;
}

// ==================== FFT: radix-16 Stockham, N=4096, 3 stages ==============
// Stage s in {1,16,256}: j=tid in [0,256), q=j&(s-1), p=j/s.
// read x_r = X[j+256r]; u = DFT16(x); v_k = u_k * W_4096^{p*s*k};
// write Y[q + 16*p*s + k*s]. LDS pad-swizzle: addr' = a + (a>>4) (verified
// uniform bank load for every stage's read AND write patterns).
#define FPAD(a) ((a) + ((a) >> 4))
#define LDSN 4352

__device__ __forceinline__ float2 cmul(float2 a, float2 b) {
  return make_float2(a.x * b.x - a.y * b.y, a.x * b.y + a.y * b.x);
}

__device__ __forceinline__ void dft16(float2* x)
{
  // w16[k] = exp(-2*pi*i*k/16)
  const float C1 = 0.9238795325112867f, S1 = 0.3826834323650898f;
  const float C2 = 0.7071067811865476f;
  const float2 w16[16] = {
    { 1.f, 0.f}, { C1,-S1}, { C2,-C2}, { S1,-C1},
    { 0.f,-1.f}, {-S1,-C1}, {-C2,-C2}, {-C1,-S1},
    {-1.f, 0.f}, {-C1, S1}, {-C2, C2}, {-S1, C1},
    { 0.f, 1.f}, { S1, C1}, { C2, C2}, { C1, S1}};
  float2 y[16];
#pragma unroll
  for (int jj = 0; jj < 4; jj++) {
    float2 a = x[jj], b = x[jj + 4], c = x[jj + 8], d = x[jj + 12];
    float2 t0 = make_float2(a.x + c.x, a.y + c.y);
    float2 t1 = make_float2(a.x - c.x, a.y - c.y);
    float2 t2 = make_float2(b.x + d.x, b.y + d.y);
    float2 t3 = make_float2(b.x - d.x, b.y - d.y);
    float2 u0 = make_float2(t0.x + t2.x, t0.y + t2.y);
    float2 u2 = make_float2(t0.x - t2.x, t0.y - t2.y);
    float2 u1 = make_float2(t1.x + t3.y, t1.y - t3.x);  // t1 - i*t3
    float2 u3 = make_float2(t1.x - t3.y, t1.y + t3.x);  // t1 + i*t3
    y[4 * jj + 0] = u0;
    y[4 * jj + 1] = cmul(u1, w16[(jj * 1) & 15]);
    y[4 * jj + 2] = cmul(u2, w16[(jj * 2) & 15]);
    y[4 * jj + 3] = cmul(u3, w16[(jj * 3) & 15]);
  }
#pragma unroll
  for (int jj = 0; jj < 4; jj++) {
    float2 a = y[jj], b = y[jj + 4], c = y[jj + 8], d = y[jj + 12];
    float2 t0 = make_float2(a.x + c.x, a.y + c.y);
    float2 t1 = make_float2(a.x - c.x, a.y - c.y);
    float2 t2 = make_float2(b.x + d.x, b.y + d.y);
    float2 t3 = make_float2(b.x - d.x, b.y - d.y);
    x[jj + 0]  = make_float2(t0.x + t2.x, t0.y + t2.y);
    x[jj + 8]  = make_float2(t0.x - t2.x, t0.y - t2.y);
    x[jj + 4]  = make_float2(t1.x + t3.y, t1.y - t3.x);
    x[jj + 12] = make_float2(t1.x - t3.y, t1.y + t3.x);
  }
}

template<int S, bool PADOUT>
__device__ __forceinline__ void fft_stage(const float2* __restrict__ Xs,
                                          float2* __restrict__ Ys, int j)
{
  float2 x[16];
#pragma unroll
  for (int r = 0; r < 16; r++) { int a = j + 256 * r; x[r] = Xs[FPAD(a)]; }
  dft16(x);
  if (S < 256) {
    int p = (S == 1) ? j : (j >> 4);
    float ang = -1.5339807878856412e-3f * (float)(p * S);  // -2*pi/4096 * p*s
    float2 w; __sincosf(ang, &w.y, &w.x);
    float2 t = w;
#pragma unroll
    for (int k = 1; k < 16; k++) { x[k] = cmul(x[k], t); t = cmul(t, w); }
  }
  const int q = j & (S - 1);
  const int base = q + ((j - q) << 4);   // q + 16*p*S
#pragma unroll
  for (int k = 0; k < 16; k++) {
    int a = base + k * S;
    Ys[PADOUT ? FPAD(a) : a] = x[k];
  }
}

// three stages: A(pad) -> B(pad) -> A(pad) -> B(unpadded), one barrier between
__device__ __forceinline__ void fft4096(float2* Abuf, float2* Bbuf, int tid)
{
  fft_stage<1, true>(Abuf, Bbuf, tid);   __syncthreads();
  fft_stage<16, true>(Bbuf, Abuf, tid);  __syncthreads();
  fft_stage<256, false>(Abuf, Bbuf, tid); __syncthreads();
}

// One workgroup per (b*H+h, d-group of 4). Packs z = q + i*k, FFTs, unpacks
// Qf,Kf via Hermitian split, accumulates G = Qf*conj(Kf) over its 4 channels
// in registers, writes a partial spectrum (no atomics).
__global__ __launch_bounds__(256)
void fft_fwd_kernel(const float* __restrict__ Qt, const float* __restrict__ Kt,
                    float* __restrict__ P)
{
  __shared__ __attribute__((aligned(16))) float2 Abuf[LDSN];
  __shared__ __attribute__((aligned(16))) float2 Bbuf[LDSN];
  const int tid = threadIdx.x;
  const int bh = blockIdx.x;      // 0..31
  const int g  = blockIdx.y;      // 0..15
  float2 accv[16];
#pragma unroll
  for (int r = 0; r < 16; r++) accv[r] = make_float2(0.f, 0.f);

  for (int dd = 0; dd < 4; dd++) {
    int d = g * 4 + dd;
    const float* q = Qt + ((size_t)bh * DK_ + d) * L_;
    const float* k = Kt + ((size_t)bh * DK_ + d) * L_;
#pragma unroll
    for (int r = 0; r < 4; r++) {
      int t = (tid + 256 * r) * 4;
      float4 qv = *(const float4*)(q + t);
      float4 kv = *(const float4*)(k + t);
      int pa = FPAD(t);     // t..t+3 share (t>>4), so pa..pa+3 contiguous
      Abuf[pa]     = make_float2(qv.x, kv.x);
      Abuf[pa + 1] = make_float2(qv.y, kv.y);
      Abuf[pa + 2] = make_float2(qv.z, kv.z);
      Abuf[pa + 3] = make_float2(qv.w, kv.w);
    }
    __syncthreads();
    fft4096(Abuf, Bbuf, tid);    // result in Bbuf, unpadded; ends with barrier
#pragma unroll
    for (int r = 0; r < 16; r++) {
      int f = tid + 256 * r;
      float2 zf = Bbuf[f];
      float2 zc = Bbuf[(L_ - f) & (L_ - 1)];
      float qr = 0.5f * (zf.x + zc.x);       // Qf = (Z[f]+conj(Z[N-f]))/2
      float qi = 0.5f * (zf.y - zc.y);
      float kr = 0.5f * (zf.y + zc.y);       // Kf = (Z[f]-conj(Z[N-f]))/(2i)
      float ki = 0.5f * (zc.x - zf.x);
      accv[r].x += qr * kr + qi * ki;        // G = Qf * conj(Kf)
      accv[r].y += qi * kr - qr * ki;
    }
    __syncthreads();   // unpack reads of Bbuf done before next pack/stage1
  }
  float2* Pp = (float2*)P + ((size_t)bh * 16 + g) * L_;
#pragma unroll
  for (int r = 0; r < 16; r++) Pp[tid + 256 * r] = accv[r];
}

// ================= fused: sum partials + inverse FFT + top-16 + softmax =====
// corr = Re(FFT(conj(S)))/N / Dk. One workgroup per (b,h).
__global__ __launch_bounds__(256)
void fft_inv_topk_kernel(const float* __restrict__ P, float* __restrict__ w,
                         int* __restrict__ delays)
{
  __shared__ __attribute__((aligned(16))) float2 Abuf[LDSN];
  __shared__ __attribute__((aligned(16))) float2 Bbuf[LDSN];
  __shared__ float swv[4];
  __shared__ int   swi[4];
  __shared__ float topv[TOPK];
  __shared__ int   topi[TOPK];
  __shared__ int   winner;
  const int tid = threadIdx.x;
  const int bh = blockIdx.x;
  const float4* Pp4 = (const float4*)(P + (size_t)bh * 16 * L_ * 2);

  // sum 16 partial spectra (float4 = 2 complex), conj, write padded
#pragma unroll
  for (int cc = 0; cc < 8; cc++) {
    int c = tid + 256 * cc;            // float4 chunk -> f = 2c, 2c+1
    float4 s = make_float4(0.f, 0.f, 0.f, 0.f);
#pragma unroll
    for (int g = 0; g < 16; g++) {
      float4 v = Pp4[(size_t)g * 2048 + c];
      s.x += v.x; s.y += v.y; s.z += v.z; s.w += v.w;
    }
    int pa = FPAD(2 * c);              // 2c,2c+1 share (a>>4)
    Abuf[pa]     = make_float2(s.x, -s.y);
    Abuf[pa + 1] = make_float2(s.z, -s.w);
  }
  __syncthreads();
  fft4096(Abuf, Bbuf, tid);            // result in Bbuf, unpadded

  const float scale = 1.0f / ((float)L_ * (float)DK_);
  float v[16];
#pragma unroll
  for (int r = 0; r < 16; r++) v[r] = Bbuf[tid + 256 * r].x * scale;

  // iterative top-16 (lowest index wins ties), values live in registers
  for (int it = 0; it < TOPK; it++) {
    float bv = -INFINITY; int bi = 0;
#pragma unroll
    for (int r = 0; r < 16; r++) {
      if (v[r] > bv) { bv = v[r]; bi = tid + 256 * r; }  // ascending f
    }
#pragma unroll
    for (int off = 32; off > 0; off >>= 1) {
      float ov = __shfl_down(bv, off, 64);
      int   oi = __shfl_down(bi, off, 64);
      if (ov > bv || (ov == bv && oi < bi)) { bv = ov; bi = oi; }
    }
    if ((tid & 63) == 0) { swv[tid >> 6] = bv; swi[tid >> 6] = bi; }
    __syncthreads();
    if (tid == 0) {
      float mv = swv[0]; int mi = swi[0];
#pragma unroll
      for (int q = 1; q < 4; q++)
        if (swv[q] > mv || (swv[q] == mv && swi[q] < mi)) { mv = swv[q]; mi = swi[q]; }
      topv[it] = mv; topi[it] = mi; winner = mi;
    }
    __syncthreads();
    int win = winner;
    if ((win & 255) == tid) v[win >> 8] = -INFINITY;
  }
  if (tid == 0) {
    float mx = topv[0];
    for (int j = 1; j < TOPK; j++) mx = fmaxf(mx, topv[j]);
    float e[TOPK]; float se = 0.f;
    for (int j = 0; j < TOPK; j++) { e[j] = expf(topv[j] - mx); se += e[j]; }
    float inv = 1.0f / se;
    for (int j = 0; j < TOPK; j++) {
      w[bh * TOPK + j] = e[j] * inv;
      delays[bh * TOPK + j] = topi[j];
    }
  }
}

// ============================ delay gather ==================================
// V bf16 [b][h][t][d]; writes ctx pre-split (hi/lo bf16) for the O-GEMM.
__global__ __launch_bounds__(256)
void gather_kernel(const unsigned short* __restrict__ V, const float* __restrict__ w,
                   const int* __restrict__ delays,
                   unsigned short* __restrict__ ctxh, unsigned short* __restrict__ ctxl)
{
  const int bh = blockIdx.x;
  const int b = bh >> 3, h = bh & 7;
  const int t0 = blockIdx.y * 16;
  __shared__ float ws[TOPK];
  __shared__ int   dls[TOPK];
  const int tid = threadIdx.x;
  if (tid < TOPK) { ws[tid] = w[bh * TOPK + tid]; dls[tid] = delays[bh * TOPK + tid]; }
  __syncthreads();
  const int t  = t0 + (tid >> 4);
  const int d4 = (tid & 15) * 4;
  const unsigned short* Vh = V + (size_t)bh * L_ * DK_;
  float ax = 0.f, ay = 0.f, az = 0.f, aw = 0.f;
#pragma unroll
  for (int j = 0; j < TOPK; j++) {
    int row = (t - dls[j]) & (L_ - 1);
    ushort4 vv = *(const ushort4*)(Vh + (size_t)row * DK_ + d4);
    float wj = ws[j];
    ax += wj * bf2f(vv.x); ay += wj * bf2f(vv.y);
    az += wj * bf2f(vv.z); aw += wj * bf2f(vv.w);
  }
  ushort4 h4, l4;
  splitf(ax, h4.x, l4.x); splitf(ay, h4.y, l4.y);
  splitf(az, h4.z, l4.z); splitf(aw, h4.w, l4.w);
  size_t off = ((size_t)(b * L_ + t) * DM_) + h * DK_ + d4;
  *(ushort4*)(ctxh + off) = h4;
  *(ushort4*)(ctxl + off) = l4;
}

// ============================ launch ========================================
extern "C" void kernel_launch(void* const* d_in, const int* in_sizes, int n_in,
                              void* d_out, int out_size, void* d_ws, size_t ws_size,
                              hipStream_t stream)
{
  const float* x  = (const float*)d_in[0];
  const float* Wq = (const float*)d_in[1];
  const float* bq = (const float*)d_in[2];
  const float* Wk = (const float*)d_in[3];
  const float* bk = (const float*)d_in[4];
  const float* Wv = (const float*)d_in[5];
  const float* bv = (const float*)d_in[6];
  const float* Wo = (const float*)d_in[7];
  const float* bo = (const float*)d_in[8];
  float* out = (float*)d_out;
  float* ws  = (float*)d_ws;

  // workspace layout (float indices). Peak ~105 MB.
  float* Qt = ws;                                   // 8,388,608 f  [b][h][d][t]
  float* Kt = ws + 8388608;                         // 8,388,608 f  [b][h][d][t]
  unsigned short* Vv = (unsigned short*)(ws + 16777216);   // bf16 [b][h][t][d]
  float* P  = ws + 20971520;                        // 4,194,304 f  partial spectra
  unsigned short* Wsp = (unsigned short*)(ws + 25165824);  // 8 x 262,144 bf16
  float* wbuf = ws + 26345472;                      // 512
  int*   dbuf = (int*)(ws + 26345984);              // 512
  // ctx splits alias Qt (dead after fft_fwd)
  unsigned short* ctxh = (unsigned short*)ws;
  unsigned short* ctxl = (unsigned short*)(ws + 4194304);

  unsigned short* Wqh = Wsp;            unsigned short* Wql = Wsp + 262144;
  unsigned short* Wkh = Wsp + 524288;   unsigned short* Wkl = Wsp + 786432;
  unsigned short* Wvh = Wsp + 1048576;  unsigned short* Wvl = Wsp + 1310720;
  unsigned short* Woh = Wsp + 1572864;  unsigned short* Wol = Wsp + 1835008;

  split_kernel<<<256, 256, 0, stream>>>(Wq, Wqh, Wql, 65536);
  split_kernel<<<256, 256, 0, stream>>>(Wk, Wkh, Wkl, 65536);
  split_kernel<<<256, 256, 0, stream>>>(Wv, Wvh, Wvl, 65536);
  split_kernel<<<256, 256, 0, stream>>>(Wo, Woh, Wol, 65536);

  dim3 gGemm(MTOT / 128, DM_ / 128);    // (128, 4)
  mfma_gemm<2, false><<<gGemm, 256, 0, stream>>>(x, nullptr, nullptr, Wqh, Wql, bq, Qt);
  mfma_gemm<2, false><<<gGemm, 256, 0, stream>>>(x, nullptr, nullptr, Wkh, Wkl, bk, Kt);
  mfma_gemm<1, false><<<gGemm, 256, 0, stream>>>(x, nullptr, nullptr, Wvh, Wvl, bv, Vv);

  fft_fwd_kernel<<<dim3(32, 16), 256, 0, stream>>>(Qt, Kt, P);
  fft_inv_topk_kernel<<<32, 256, 0, stream>>>(P, wbuf, dbuf);
  gather_kernel<<<dim3(32, L_ / 16), 256, 0, stream>>>(Vv, wbuf, dbuf, ctxh, ctxl);

  mfma_gemm<0, true><<<gGemm, 256, 0, stream>>>(nullptr, ctxh, ctxl, Woh, Wol, bo, out);
}

// Round 4
// 295.016 us; speedup vs baseline: 2.2873x; 1.0709x over previous
//
#include <hip/hip_runtime.h>
#include <math.h>

#define L_   4096
#define DM_  512
#define B_   4
#define H_   8
#define DK_  64
#define MTOT (B_*L_)      // 16384
#define TOPK 16

typedef __bf16 bf16x8 __attribute__((ext_vector_type(8)));
typedef float  f32x4  __attribute__((ext_vector_type(4)));

// ---------------------------------------------------------------- helpers ---
__device__ __forceinline__ void splitf(float x, unsigned short& h, unsigned short& l) {
  unsigned int u = __float_as_uint(x);
  h = (unsigned short)(u >> 16);                       // truncated hi
  float hf = __uint_as_float(u & 0xFFFF0000u);
  l = (unsigned short)(__float_as_uint(x - hf) >> 16); // truncated lo
}
__device__ __forceinline__ unsigned short f2bf_rne(float f) {
  unsigned int u = __float_as_uint(f);
  return (unsigned short)((u + 0x7FFFu + ((u >> 16) & 1u)) >> 16);
}
__device__ __forceinline__ float bf2f(unsigned short u) {
  return __uint_as_float(((unsigned int)u) << 16);
}

// async 16B/lane global->LDS stage of a 128x32 bf16 tile from a row-major
// source with row stride 512 elements. LDS layout: [128][32] contiguous.
__device__ __forceinline__ void stage_tile_async(const unsigned short* __restrict__ g,
                                                 int row0, int k0,
                                                 unsigned short* lds, int tid) {
  const int wave = tid >> 6;
#pragma unroll
  for (int it = 0; it < 2; ++it) {
    int slot = it * 256 + tid;          // 0..511
    int row  = slot >> 2;               // 0..127
    int ch   = slot & 3;                // 16B chunk within 64B row
    const unsigned short* gp = g + (size_t)(row0 + row) * 512 + k0 + ch * 8;
    unsigned short* lp = lds + (size_t)(it * 256 + wave * 64) * 8;  // wave-uniform base
    __builtin_amdgcn_global_load_lds(
        (const __attribute__((address_space(1))) unsigned int*)gp,
        (__attribute__((address_space(3))) unsigned int*)lp, 16, 0, 0);
  }
}

// =============== fused QKV GEMM: [Q|K|V] = x @ [Wq|Wk|Wv]^T + b =============
// M=16384, N=1536 (3 segments of 512), K=512. 128x128 tile, BK=32, 4 waves.
// 3-pass split bf16. All operands pre-split, fully async staging.
// seg 0 -> Qt fp32 [b][h][d][t]; seg 1 -> Kt fp32 [b][h][d][t];
// seg 2 -> Vv bf16 [b][h][t][d].
__global__ __launch_bounds__(256)
void qkv_gemm(const unsigned short* __restrict__ xh, const unsigned short* __restrict__ xl,
              const unsigned short* __restrict__ Wh, const unsigned short* __restrict__ Wl,
              const float* __restrict__ bq, const float* __restrict__ bk,
              const float* __restrict__ bv,
              float* __restrict__ Qt, float* __restrict__ Kt,
              unsigned short* __restrict__ Vv)
{
  __shared__ __attribute__((aligned(16))) unsigned short AhS[128 * 32];
  __shared__ __attribute__((aligned(16))) unsigned short AlS[128 * 32];
  __shared__ __attribute__((aligned(16))) unsigned short BhS[128 * 32];
  __shared__ __attribute__((aligned(16))) unsigned short BlS[128 * 32];

  const int tid  = threadIdx.x;
  const int lane = tid & 63, wave = tid >> 6;
  const int m0 = blockIdx.x * 128, n0 = blockIdx.y * 128;
  const int wm = (wave >> 1) * 64, wn = (wave & 1) * 64;
  const int fr = lane & 15, fq = lane >> 4;

  f32x4 acc[4][4];
#pragma unroll
  for (int i = 0; i < 4; i++)
#pragma unroll
    for (int j = 0; j < 4; j++) acc[i][j] = (f32x4){0.f, 0.f, 0.f, 0.f};

  for (int k0 = 0; k0 < 512; k0 += 32) {
    stage_tile_async(xh, m0, k0, AhS, tid);
    stage_tile_async(xl, m0, k0, AlS, tid);
    stage_tile_async(Wh, n0, k0, BhS, tid);
    stage_tile_async(Wl, n0, k0, BlS, tid);
    __syncthreads();

    bf16x8 ah[4], al[4], bh[4], bl[4];
#pragma unroll
    for (int t = 0; t < 4; ++t) {
      ah[t] = *(const bf16x8*)&AhS[(wm + t * 16 + fr) * 32 + fq * 8];
      al[t] = *(const bf16x8*)&AlS[(wm + t * 16 + fr) * 32 + fq * 8];
      bh[t] = *(const bf16x8*)&BhS[(wn + t * 16 + fr) * 32 + fq * 8];
      bl[t] = *(const bf16x8*)&BlS[(wn + t * 16 + fr) * 32 + fq * 8];
    }
#pragma unroll
    for (int mt = 0; mt < 4; ++mt)
#pragma unroll
      for (int nt = 0; nt < 4; ++nt) {
        acc[mt][nt] = __builtin_amdgcn_mfma_f32_16x16x32_bf16(ah[mt], bh[nt], acc[mt][nt], 0, 0, 0);
        acc[mt][nt] = __builtin_amdgcn_mfma_f32_16x16x32_bf16(ah[mt], bl[nt], acc[mt][nt], 0, 0, 0);
        acc[mt][nt] = __builtin_amdgcn_mfma_f32_16x16x32_bf16(al[mt], bh[nt], acc[mt][nt], 0, 0, 0);
      }
    __syncthreads();
  }

  const int seg = (int)(blockIdx.y >> 2);   // 0:Q 1:K 2:V (block-uniform)
  const float* bias = (seg == 0) ? bq : (seg == 1) ? bk : bv;
  const int nseg0 = seg * 512;
  float* QKdst = (seg == 0) ? Qt : Kt;

#pragma unroll
  for (int nt = 0; nt < 4; ++nt) {
    const int n  = n0 + wn + nt * 16 + fr;
    const int nl = n - nseg0;
    const float bb = bias[nl];
    const int h = nl >> 6, d = nl & 63;
#pragma unroll
    for (int mt = 0; mt < 4; ++mt) {
      const int mb = m0 + wm + mt * 16 + fq * 4;
      f32x4 a = acc[mt][nt];
      if (seg < 2) {
        const int b = mb >> 12, l0 = mb & (L_ - 1);
        float4 st = make_float4(a[0] + bb, a[1] + bb, a[2] + bb, a[3] + bb);
        *(float4*)(QKdst + ((size_t)(b * H_ + h) * DK_ + d) * L_ + l0) = st;
      } else {
#pragma unroll
        for (int r = 0; r < 4; ++r) {
          int m = mb + r;
          int b = m >> 12, l = m & (L_ - 1);
          Vv[((size_t)(b * H_ + h) * L_ + l) * DK_ + d] = f2bf_rne(a[r] + bb);
        }
      }
    }
  }
}

// ====================== O GEMM: out = ctx @ Wo^T + bias =====================
__global__ __launch_bounds__(256)
void o_gemm(const unsigned short* __restrict__ Ah, const unsigned short* __restrict__ Al,
            const unsigned short* __restrict__ Bh, const unsigned short* __restrict__ Bl,
            const float* __restrict__ bias, float* __restrict__ Cout)
{
  __shared__ __attribute__((aligned(16))) unsigned short AhS[128 * 32];
  __shared__ __attribute__((aligned(16))) unsigned short AlS[128 * 32];
  __shared__ __attribute__((aligned(16))) unsigned short BhS[128 * 32];
  __shared__ __attribute__((aligned(16))) unsigned short BlS[128 * 32];

  const int tid  = threadIdx.x;
  const int lane = tid & 63, wave = tid >> 6;
  const int m0 = blockIdx.x * 128, n0 = blockIdx.y * 128;
  const int wm = (wave >> 1) * 64, wn = (wave & 1) * 64;
  const int fr = lane & 15, fq = lane >> 4;

  f32x4 acc[4][4];
#pragma unroll
  for (int i = 0; i < 4; i++)
#pragma unroll
    for (int j = 0; j < 4; j++) acc[i][j] = (f32x4){0.f, 0.f, 0.f, 0.f};

  for (int k0 = 0; k0 < 512; k0 += 32) {
    stage_tile_async(Ah, m0, k0, AhS, tid);
    stage_tile_async(Al, m0, k0, AlS, tid);
    stage_tile_async(Bh, n0, k0, BhS, tid);
    stage_tile_async(Bl, n0, k0, BlS, tid);
    __syncthreads();

    bf16x8 ah[4], al[4], bh[4], bl[4];
#pragma unroll
    for (int t = 0; t < 4; ++t) {
      ah[t] = *(const bf16x8*)&AhS[(wm + t * 16 + fr) * 32 + fq * 8];
      al[t] = *(const bf16x8*)&AlS[(wm + t * 16 + fr) * 32 + fq * 8];
      bh[t] = *(const bf16x8*)&BhS[(wn + t * 16 + fr) * 32 + fq * 8];
      bl[t] = *(const bf16x8*)&BlS[(wn + t * 16 + fr) * 32 + fq * 8];
    }
#pragma unroll
    for (int mt = 0; mt < 4; ++mt)
#pragma unroll
      for (int nt = 0; nt < 4; ++nt) {
        acc[mt][nt] = __builtin_amdgcn_mfma_f32_16x16x32_bf16(ah[mt], bh[nt], acc[mt][nt], 0, 0, 0);
        acc[mt][nt] = __builtin_amdgcn_mfma_f32_16x16x32_bf16(ah[mt], bl[nt], acc[mt][nt], 0, 0, 0);
        acc[mt][nt] = __builtin_amdgcn_mfma_f32_16x16x32_bf16(al[mt], bh[nt], acc[mt][nt], 0, 0, 0);
      }
    __syncthreads();
  }

#pragma unroll
  for (int nt = 0; nt < 4; ++nt) {
    const int n = n0 + wn + nt * 16 + fr;
    const float bb = bias[n];
#pragma unroll
    for (int mt = 0; mt < 4; ++mt) {
      const int mb = m0 + wm + mt * 16 + fq * 4;
      f32x4 a = acc[mt][nt];
#pragma unroll
      for (int r = 0; r < 4; ++r) {
        int m = mb + r;
        Cout[(size_t)m * DM_ + n] = a[r] + bb;
      }
    }
  }
}

// ============== one-shot split: x and all 4 weights -> hi/lo bf16 ===========
// chunks: x = 2,097,152 float4; each W = 65,536 float4. total 2,359,296.
__global__ __launch_bounds__(256)
void split_all(const float* __restrict__ x,  const float* __restrict__ Wq,
               const float* __restrict__ Wk, const float* __restrict__ Wv,
               const float* __restrict__ Wo,
               unsigned short* __restrict__ xh,    unsigned short* __restrict__ xl,
               unsigned short* __restrict__ Wqkvh, unsigned short* __restrict__ Wqkvl,
               unsigned short* __restrict__ Woh,   unsigned short* __restrict__ Wol)
{
  int i = blockIdx.x * 256 + threadIdx.x;
  const float* src; unsigned short* dh; unsigned short* dl; int off;
  if (i < 2097152) { src = x; dh = xh; dl = xl; off = i; }
  else {
    int j = i - 2097152; int seg = j >> 16; off = j & 65535;
    if (seg == 0)      { src = Wq; dh = Wqkvh;          dl = Wqkvl; }
    else if (seg == 1) { src = Wk; dh = Wqkvh + 262144; dl = Wqkvl + 262144; }
    else if (seg == 2) { src = Wv; dh = Wqkvh + 524288; dl = Wqkvl + 524288; }
    else               { src = Wo; dh = Woh;            dl = Wol; }
  }
  float4 v = ((const float4*)src)[off];
  ushort4 h, l;
  splitf(v.x, h.x, l.x); splitf(v.y, h.y, l.y);
  splitf(v.z, h.z, l.z); splitf(v.w, h.w, l.w);
  ((ushort4*)dh)[off] = h;
  ((ushort4*)dl)[off] = l;
}

// ==================== FFT: radix-16 Stockham, N=4096, 3 stages ==============
#define FPAD(a) ((a) + ((a) >> 4))
#define LDSN 4352

__device__ __forceinline__ float2 cmul(float2 a, float2 b) {
  return make_float2(a.x * b.x - a.y * b.y, a.x * b.y + a.y * b.x);
}

__device__ __forceinline__ void dft16(float2* x)
{
  const float C1 = 0.9238795325112867f, S1 = 0.3826834323650898f;
  const float C2 = 0.7071067811865476f;
  const float2 w16[16] = {
    { 1.f, 0.f}, { C1,-S1}, { C2,-C2}, { S1,-C1},
    { 0.f,-1.f}, {-S1,-C1}, {-C2,-C2}, {-C1,-S1},
    {-1.f, 0.f}, {-C1, S1}, {-C2, C2}, {-S1, C1},
    { 0.f, 1.f}, { S1, C1}, { C2, C2}, { C1, S1}};
  float2 y[16];
#pragma unroll
  for (int jj = 0; jj < 4; jj++) {
    float2 a = x[jj], b = x[jj + 4], c = x[jj + 8], d = x[jj + 12];
    float2 t0 = make_float2(a.x + c.x, a.y + c.y);
    float2 t1 = make_float2(a.x - c.x, a.y - c.y);
    float2 t2 = make_float2(b.x + d.x, b.y + d.y);
    float2 t3 = make_float2(b.x - d.x, b.y - d.y);
    float2 u0 = make_float2(t0.x + t2.x, t0.y + t2.y);
    float2 u2 = make_float2(t0.x - t2.x, t0.y - t2.y);
    float2 u1 = make_float2(t1.x + t3.y, t1.y - t3.x);
    float2 u3 = make_float2(t1.x - t3.y, t1.y + t3.x);
    y[4 * jj + 0] = u0;
    y[4 * jj + 1] = cmul(u1, w16[(jj * 1) & 15]);
    y[4 * jj + 2] = cmul(u2, w16[(jj * 2) & 15]);
    y[4 * jj + 3] = cmul(u3, w16[(jj * 3) & 15]);
  }
#pragma unroll
  for (int jj = 0; jj < 4; jj++) {
    float2 a = y[jj], b = y[jj + 4], c = y[jj + 8], d = y[jj + 12];
    float2 t0 = make_float2(a.x + c.x, a.y + c.y);
    float2 t1 = make_float2(a.x - c.x, a.y - c.y);
    float2 t2 = make_float2(b.x + d.x, b.y + d.y);
    float2 t3 = make_float2(b.x - d.x, b.y - d.y);
    x[jj + 0]  = make_float2(t0.x + t2.x, t0.y + t2.y);
    x[jj + 8]  = make_float2(t0.x - t2.x, t0.y - t2.y);
    x[jj + 4]  = make_float2(t1.x + t3.y, t1.y - t3.x);
    x[jj + 12] = make_float2(t1.x - t3.y, t1.y + t3.x);
  }
}

template<int S, bool PADOUT>
__device__ __forceinline__ void fft_stage(const float2* __restrict__ Xs,
                                          float2* __restrict__ Ys, int j)
{
  float2 x[16];
#pragma unroll
  for (int r = 0; r < 16; r++) { int a = j + 256 * r; x[r] = Xs[FPAD(a)]; }
  dft16(x);
  if (S < 256) {
    int p = (S == 1) ? j : (j >> 4);
    float ang = -1.5339807878856412e-3f * (float)(p * S);  // -2*pi/4096 * p*s
    float2 w; __sincosf(ang, &w.y, &w.x);
    float2 t = w;
#pragma unroll
    for (int k = 1; k < 16; k++) { x[k] = cmul(x[k], t); t = cmul(t, w); }
  }
  const int q = j & (S - 1);
  const int base = q + ((j - q) << 4);   // q + 16*p*S
#pragma unroll
  for (int k = 0; k < 16; k++) {
    int a = base + k * S;
    Ys[PADOUT ? FPAD(a) : a] = x[k];
  }
}

__device__ __forceinline__ void fft4096(float2* Abuf, float2* Bbuf, int tid)
{
  fft_stage<1, true>(Abuf, Bbuf, tid);   __syncthreads();
  fft_stage<16, true>(Bbuf, Abuf, tid);  __syncthreads();
  fft_stage<256, false>(Abuf, Bbuf, tid); __syncthreads();
}

// One workgroup per (b*H+h, d-group of 2). grid (32, 32).
__global__ __launch_bounds__(256)
void fft_fwd_kernel(const float* __restrict__ Qt, const float* __restrict__ Kt,
                    float* __restrict__ P)
{
  __shared__ __attribute__((aligned(16))) float2 Abuf[LDSN];
  __shared__ __attribute__((aligned(16))) float2 Bbuf[LDSN];
  const int tid = threadIdx.x;
  const int bh = blockIdx.x;      // 0..31
  const int g  = blockIdx.y;      // 0..31
  float2 accv[16];
#pragma unroll
  for (int r = 0; r < 16; r++) accv[r] = make_float2(0.f, 0.f);

  for (int dd = 0; dd < 2; dd++) {
    int d = g * 2 + dd;
    const float* q = Qt + ((size_t)bh * DK_ + d) * L_;
    const float* k = Kt + ((size_t)bh * DK_ + d) * L_;
#pragma unroll
    for (int r = 0; r < 4; r++) {
      int t = (tid + 256 * r) * 4;
      float4 qv = *(const float4*)(q + t);
      float4 kv = *(const float4*)(k + t);
      int pa = FPAD(t);
      Abuf[pa]     = make_float2(qv.x, kv.x);
      Abuf[pa + 1] = make_float2(qv.y, kv.y);
      Abuf[pa + 2] = make_float2(qv.z, kv.z);
      Abuf[pa + 3] = make_float2(qv.w, kv.w);
    }
    __syncthreads();
    fft4096(Abuf, Bbuf, tid);    // result in Bbuf, unpadded; ends with barrier
#pragma unroll
    for (int r = 0; r < 16; r++) {
      int f = tid + 256 * r;
      float2 zf = Bbuf[f];
      float2 zc = Bbuf[(L_ - f) & (L_ - 1)];
      float qr = 0.5f * (zf.x + zc.x);
      float qi = 0.5f * (zf.y - zc.y);
      float kr = 0.5f * (zf.y + zc.y);
      float ki = 0.5f * (zc.x - zf.x);
      accv[r].x += qr * kr + qi * ki;        // G = Qf * conj(Kf)
      accv[r].y += qi * kr - qr * ki;
    }
    __syncthreads();
  }
  float2* Pp = (float2*)P + ((size_t)bh * 32 + g) * L_;
#pragma unroll
  for (int r = 0; r < 16; r++) Pp[tid + 256 * r] = accv[r];
}

// ================= fused: sum partials + inverse FFT + top-16 + softmax =====
__global__ __launch_bounds__(256)
void fft_inv_topk_kernel(const float* __restrict__ P, float* __restrict__ w,
                         int* __restrict__ delays)
{
  __shared__ __attribute__((aligned(16))) float2 Abuf[LDSN];
  __shared__ __attribute__((aligned(16))) float2 Bbuf[LDSN];
  __shared__ float swv[4];
  __shared__ int   swi[4];
  __shared__ float topv[TOPK];
  __shared__ int   topi[TOPK];
  __shared__ int   winner;
  const int tid = threadIdx.x;
  const int bh = blockIdx.x;
  const float4* Pp4 = (const float4*)(P + (size_t)bh * 32 * L_ * 2);

#pragma unroll
  for (int cc = 0; cc < 8; cc++) {
    int c = tid + 256 * cc;            // float4 chunk -> f = 2c, 2c+1
    float4 s = make_float4(0.f, 0.f, 0.f, 0.f);
#pragma unroll
    for (int g = 0; g < 32; g++) {
      float4 v = Pp4[(size_t)g * 2048 + c];
      s.x += v.x; s.y += v.y; s.z += v.z; s.w += v.w;
    }
    int pa = FPAD(2 * c);
    Abuf[pa]     = make_float2(s.x, -s.y);
    Abuf[pa + 1] = make_float2(s.z, -s.w);
  }
  __syncthreads();
  fft4096(Abuf, Bbuf, tid);            // result in Bbuf, unpadded

  const float scale = 1.0f / ((float)L_ * (float)DK_);
  float v[16];
#pragma unroll
  for (int r = 0; r < 16; r++) v[r] = Bbuf[tid + 256 * r].x * scale;

  for (int it = 0; it < TOPK; it++) {
    float bv = -INFINITY; int bi = 0;
#pragma unroll
    for (int r = 0; r < 16; r++) {
      if (v[r] > bv) { bv = v[r]; bi = tid + 256 * r; }
    }
#pragma unroll
    for (int off = 32; off > 0; off >>= 1) {
      float ov = __shfl_down(bv, off, 64);
      int   oi = __shfl_down(bi, off, 64);
      if (ov > bv || (ov == bv && oi < bi)) { bv = ov; bi = oi; }
    }
    if ((tid & 63) == 0) { swv[tid >> 6] = bv; swi[tid >> 6] = bi; }
    __syncthreads();
    if (tid == 0) {
      float mv = swv[0]; int mi = swi[0];
#pragma unroll
      for (int q = 1; q < 4; q++)
        if (swv[q] > mv || (swv[q] == mv && swi[q] < mi)) { mv = swv[q]; mi = swi[q]; }
      topv[it] = mv; topi[it] = mi; winner = mi;
    }
    __syncthreads();
    int win = winner;
    if ((win & 255) == tid) v[win >> 8] = -INFINITY;
  }
  if (tid == 0) {
    float mx = topv[0];
    for (int j = 1; j < TOPK; j++) mx = fmaxf(mx, topv[j]);
    float e[TOPK]; float se = 0.f;
    for (int j = 0; j < TOPK; j++) { e[j] = expf(topv[j] - mx); se += e[j]; }
    float inv = 1.0f / se;
    for (int j = 0; j < TOPK; j++) {
      w[bh * TOPK + j] = e[j] * inv;
      delays[bh * TOPK + j] = topi[j];
    }
  }
}

// ============================ delay gather ==================================
__global__ __launch_bounds__(256)
void gather_kernel(const unsigned short* __restrict__ V, const float* __restrict__ w,
                   const int* __restrict__ delays,
                   unsigned short* __restrict__ ctxh, unsigned short* __restrict__ ctxl)
{
  const int bh = blockIdx.x;
  const int b = bh >> 3, h = bh & 7;
  const int t0 = blockIdx.y * 16;
  __shared__ float ws[TOPK];
  __shared__ int   dls[TOPK];
  const int tid = threadIdx.x;
  if (tid < TOPK) { ws[tid] = w[bh * TOPK + tid]; dls[tid] = delays[bh * TOPK + tid]; }
  __syncthreads();
  const int t  = t0 + (tid >> 4);
  const int d4 = (tid & 15) * 4;
  const unsigned short* Vh = V + (size_t)bh * L_ * DK_;
  float ax = 0.f, ay = 0.f, az = 0.f, aw = 0.f;
#pragma unroll
  for (int j = 0; j < TOPK; j++) {
    int row = (t - dls[j]) & (L_ - 1);
    ushort4 vv = *(const ushort4*)(Vh + (size_t)row * DK_ + d4);
    float wj = ws[j];
    ax += wj * bf2f(vv.x); ay += wj * bf2f(vv.y);
    az += wj * bf2f(vv.z); aw += wj * bf2f(vv.w);
  }
  ushort4 h4, l4;
  splitf(ax, h4.x, l4.x); splitf(ay, h4.y, l4.y);
  splitf(az, h4.z, l4.z); splitf(aw, h4.w, l4.w);
  size_t off = ((size_t)(b * L_ + t) * DM_) + h * DK_ + d4;
  *(ushort4*)(ctxh + off) = h4;
  *(ushort4*)(ctxl + off) = l4;
}

// ============================ launch ========================================
extern "C" void kernel_launch(void* const* d_in, const int* in_sizes, int n_in,
                              void* d_out, int out_size, void* d_ws, size_t ws_size,
                              hipStream_t stream)
{
  const float* x  = (const float*)d_in[0];
  const float* Wq = (const float*)d_in[1];
  const float* bq = (const float*)d_in[2];
  const float* Wk = (const float*)d_in[3];
  const float* bk = (const float*)d_in[4];
  const float* Wv = (const float*)d_in[5];
  const float* bv = (const float*)d_in[6];
  const float* Wo = (const float*)d_in[7];
  const float* bo = (const float*)d_in[8];
  float* out = (float*)d_out;
  float* ws  = (float*)d_ws;

  // workspace layout (float offsets). Peak ~121.7 MB.
  // region A: xh+xl (live through qkv_gemm), then reused as P (fft partials)
  unsigned short* xh = (unsigned short*)ws;                 // 8,388,608 bf16
  unsigned short* xl = (unsigned short*)(ws + 4194304);     // 8,388,608 bf16
  float* P  = ws;                                           // 8,388,608 f (aliases xh/xl)
  float* Qt = ws + 8388608;                                 // 8,388,608 f [b][h][d][t]
  float* Kt = ws + 16777216;                                // 8,388,608 f [b][h][d][t]
  unsigned short* Vv = (unsigned short*)(ws + 25165824);    // 8,388,608 bf16 [b][h][t][d]
  unsigned short* Wqkvh = (unsigned short*)(ws + 29360128); // 786,432 bf16
  unsigned short* Wqkvl = (unsigned short*)(ws + 29753344); // 786,432 bf16
  unsigned short* Woh   = (unsigned short*)(ws + 30146560); // 262,144 bf16
  unsigned short* Wol   = (unsigned short*)(ws + 30277632); // 262,144 bf16
  float* wbuf = ws + 30408704;                              // 512
  int*   dbuf = (int*)(ws + 30409216);                      // 512
  // ctx splits alias Qt (dead after fft_fwd)
  unsigned short* ctxh = (unsigned short*)(ws + 8388608);
  unsigned short* ctxl = (unsigned short*)(ws + 12582912);

  split_all<<<9216, 256, 0, stream>>>(x, Wq, Wk, Wv, Wo, xh, xl, Wqkvh, Wqkvl, Woh, Wol);

  qkv_gemm<<<dim3(MTOT / 128, 12), 256, 0, stream>>>(xh, xl, Wqkvh, Wqkvl,
                                                     bq, bk, bv, Qt, Kt, Vv);

  fft_fwd_kernel<<<dim3(32, 32), 256, 0, stream>>>(Qt, Kt, P);
  fft_inv_topk_kernel<<<32, 256, 0, stream>>>(P, wbuf, dbuf);
  gather_kernel<<<dim3(32, L_ / 16), 256, 0, stream>>>(Vv, wbuf, dbuf, ctxh, ctxl);

  o_gemm<<<dim3(MTOT / 128, DM_ / 128), 256, 0, stream>>>(ctxh, ctxl, Woh, Wol, bo, out);
}